// Round 3
// baseline (2374.560 us; speedup 1.0000x reference)
//
#include <hip/hip_runtime.h>
#include <math.h>

#define N_NODES 100000
#define N_EDGES 800000
#define NGRAPH  64

typedef __attribute__((ext_vector_type(8))) __bf16 bf16x8;
typedef __attribute__((ext_vector_type(4))) float f32x4;

// ---------- helpers ----------
static __device__ __forceinline__ unsigned flip_f(float x) {
  unsigned u = __float_as_uint(x);
  return u ^ ((u & 0x80000000u) ? 0xFFFFFFFFu : 0x80000000u);
}
static __device__ __forceinline__ float unflip_f(unsigned m) {
  unsigned u = m ^ ((m & 0x80000000u) ? 0x80000000u : 0xFFFFFFFFu);
  return __uint_as_float(u);
}
static __device__ __forceinline__ unsigned short f2bf(float x) {
  unsigned u = __float_as_uint(x);
  u += 0x7fffu + ((u >> 16) & 1u);   // RNE
  return (unsigned short)(u >> 16);
}
static __device__ __forceinline__ unsigned pk2(float a, float b) {
  return (unsigned)f2bf(a) | ((unsigned)f2bf(b) << 16);
}
static __device__ __forceinline__ float bf2f(unsigned short h) {
  return __uint_as_float((unsigned)h << 16);
}
static __device__ __forceinline__ void unpack8(uint4 w, float* f) {
  f[0] = __uint_as_float(w.x << 16); f[1] = __uint_as_float(w.x & 0xFFFF0000u);
  f[2] = __uint_as_float(w.y << 16); f[3] = __uint_as_float(w.y & 0xFFFF0000u);
  f[4] = __uint_as_float(w.z << 16); f[5] = __uint_as_float(w.z & 0xFFFF0000u);
  f[6] = __uint_as_float(w.w << 16); f[7] = __uint_as_float(w.w & 0xFFFF0000u);
}
static __device__ __forceinline__ uint4 pack8(const float* f) {
  uint4 w;
  w.x = pk2(f[0], f[1]); w.y = pk2(f[2], f[3]);
  w.z = pk2(f[4], f[5]); w.w = pk2(f[6], f[7]);
  return w;
}

// ---------- CSR build ----------
__global__ void hist_k(const int* __restrict__ dst, int* __restrict__ cnt) {
  int e = blockIdx.x * 256 + threadIdx.x;
  if (e < N_EDGES) atomicAdd(&cnt[dst[e]], 1);
}

__global__ void dinv_k(const int* __restrict__ cnt, float* __restrict__ dinv) {
  int i = blockIdx.x * 256 + threadIdx.x;
  if (i < N_NODES) dinv[i] = rsqrtf((float)cnt[i] + 1.0f);
}

__global__ void scan_block_k(const int* __restrict__ cnt, int* __restrict__ rs,
                             int* __restrict__ bsum) {
  __shared__ int s[256];
  int t = threadIdx.x, i = blockIdx.x * 256 + t;
  int v = (i < N_NODES) ? cnt[i] : 0;
  s[t] = v; __syncthreads();
  for (int off = 1; off < 256; off <<= 1) {
    int a = (t >= off) ? s[t - off] : 0;
    __syncthreads();
    s[t] += a;
    __syncthreads();
  }
  if (i < N_NODES) rs[i] = s[t] - v;
  if (t == 255) bsum[blockIdx.x] = s[255];
}

__global__ void scan_bsum_k(int* __restrict__ bsum, int nb) {
  __shared__ int s[512];
  int t = threadIdx.x;
  int v = (t < nb) ? bsum[t] : 0;
  s[t] = v; __syncthreads();
  for (int off = 1; off < 512; off <<= 1) {
    int a = (t >= off) ? s[t - off] : 0;
    __syncthreads();
    s[t] += a;
    __syncthreads();
  }
  if (t < nb) bsum[t] = s[t] - v;
}

__global__ void scan_add_k(int* __restrict__ rs, int* __restrict__ cursor,
                           const int* __restrict__ bsum) {
  int i = blockIdx.x * 256 + threadIdx.x;
  if (i < N_NODES) {
    int r = rs[i] + bsum[i >> 8];
    rs[i] = r;
    cursor[i] = r;
  }
}

__global__ void build_k(const int* __restrict__ src, const int* __restrict__ dst,
                        int* __restrict__ cursor, int* __restrict__ srcs) {
  int e = blockIdx.x * 256 + threadIdx.x;
  if (e < N_EDGES) {
    int d = dst[e];
    int p = atomicAdd(&cursor[d], 1);
    srcs[p] = src[e];
  }
}

__global__ void graph_starts_k(const int* __restrict__ batch, int* __restrict__ gstart) {
  int g = threadIdx.x;
  if (g > NGRAPH) return;
  if (g == NGRAPH) { gstart[NGRAPH] = N_NODES; return; }
  int lo = 0, hi = N_NODES;
  while (lo < hi) {
    int mid = (lo + hi) >> 1;
    if (batch[mid] < g) lo = mid + 1; else hi = mid;
  }
  gstart[g] = lo;
}

// ---------- MFMA bf16 GEMM: B fully LDS-resident, A direct-to-register ----------
// Block = 64 rows x BN cols (BN = 16*NT), 4 waves, wave w owns rows [w*16, w*16+16).
// K compile-time. B (K x BN slice of weights, f32) is staged once (per KT-tile)
// into LDS as bf16 [n][k] (stride STK). A fragments (8 contig bf16 = 1 dwordx4
// per lane per 32-k step) are loaded DIRECTLY from global into registers, all
// issued at block start so their latency hides under B staging.
// Steady-state compute loop has ZERO barriers (KTILES==1 for all but Wc).
template <typename AT, int K, int KT, int NT, bool OUT_F32>
__global__ __launch_bounds__(256, 2)
void gemm_t(const AT* __restrict__ A, const float* __restrict__ B,
            const float* __restrict__ bias,
            const unsigned short* __restrict__ add1,
            const unsigned short* __restrict__ add2,
            void* __restrict__ Cv, int M, int F, int relu,
            const float* __restrict__ pe3src, unsigned short* __restrict__ C2) {
  constexpr int BN = 16 * NT;
  constexpr int KTILES = K / KT;
  constexpr int NSTEP = KT / 32;     // 32-k steps per tile
  constexpr int NFRAG = K / 32;      // total A fragments per lane
  constexpr int STK = KT + 8;        // LDS row stride (bf16 elems): 2-way bank alias only
  __shared__ unsigned short Bs[BN * STK];
  const int tid = threadIdx.x;
  const int wave = tid >> 6, lane = tid & 63;
  const int quad = lane >> 4, l16 = lane & 15;
  const int row0 = blockIdx.x * 64;
  const int col0 = blockIdx.y * BN;
  const int arow = row0 + wave * 16 + l16;
  const bool aok = arow < M;

  // ---- A prologue: issue ALL fragment loads up front ----
  float4 av[sizeof(AT) == 4 ? 2 * NFRAG : 1];
  uint4 ah[sizeof(AT) == 4 ? 1 : NFRAG];
  if constexpr (sizeof(AT) == 4) {
    const float* ap = (const float*)A + (size_t)arow * K + quad * 8;
#pragma unroll
    for (int s = 0; s < NFRAG; s++) {
      av[2 * s] = aok ? *(const float4*)(ap + s * 32) : make_float4(0.f, 0.f, 0.f, 0.f);
      av[2 * s + 1] = aok ? *(const float4*)(ap + s * 32 + 4) : make_float4(0.f, 0.f, 0.f, 0.f);
    }
  } else {
    const unsigned short* ap = (const unsigned short*)A + (size_t)arow * K + quad * 8;
#pragma unroll
    for (int s = 0; s < NFRAG; s++)
      ah[s] = aok ? *(const uint4*)(ap + s * 32) : make_uint4(0, 0, 0, 0);
  }

  f32x4 acc[NT];
#pragma unroll
  for (int j = 0; j < NT; j++) acc[j] = (f32x4){0.f, 0.f, 0.f, 0.f};

#pragma unroll
  for (int kt = 0; kt < KTILES; ++kt) {
    if (kt) __syncthreads();  // protect LDS before overwrite (Wc only)
    // ---- stage B tile: cols [col0,col0+BN), k in [kt*KT, kt*KT+KT), f32->bf16 ----
    for (int idx = tid; idx < BN * (KT / 8); idx += 256) {
      int n = idx / (KT / 8);
      int oct = idx - n * (KT / 8);
      const float* bp = B + (size_t)(kt * KT + oct * 8) * F + col0 + n;
      uint4 w;
      w.x = pk2(bp[0 * (size_t)F], bp[1 * (size_t)F]);
      w.y = pk2(bp[2 * (size_t)F], bp[3 * (size_t)F]);
      w.z = pk2(bp[4 * (size_t)F], bp[5 * (size_t)F]);
      w.w = pk2(bp[6 * (size_t)F], bp[7 * (size_t)F]);
      *(uint4*)&Bs[n * STK + oct * 8] = w;
    }
    __syncthreads();
    // ---- compute: no barriers ----
#pragma unroll
    for (int s = 0; s < NSTEP; ++s) {
      const int gs = kt * NSTEP + s;
      bf16x8 afr;
      if constexpr (sizeof(AT) == 4) {
        uint4 t;
        t.x = pk2(av[2 * gs].x, av[2 * gs].y);
        t.y = pk2(av[2 * gs].z, av[2 * gs].w);
        t.z = pk2(av[2 * gs + 1].x, av[2 * gs + 1].y);
        t.w = pk2(av[2 * gs + 1].z, av[2 * gs + 1].w);
        afr = *(bf16x8*)&t;
      } else {
        afr = *(bf16x8*)&ah[gs];
      }
#pragma unroll
      for (int nt = 0; nt < NT; nt++) {
        bf16x8 bfr = *(const bf16x8*)&Bs[(nt * 16 + l16) * STK + s * 32 + quad * 8];
        acc[nt] = __builtin_amdgcn_mfma_f32_16x16x32_bf16(afr, bfr, acc[nt], 0, 0, 0);
      }
    }
  }

  // ---- epilogue ----
  float* Cf = (float*)Cv;
  unsigned short* Ch = (unsigned short*)Cv;
#pragma unroll
  for (int r = 0; r < 4; r++) {
    int row = row0 + wave * 16 + quad * 4 + r;
    if (row >= M) continue;
#pragma unroll
    for (int nt = 0; nt < NT; nt++) {
      int col = col0 + nt * 16 + l16;
      float v = acc[nt][r];
      if (bias) v += bias[col];
      if (relu) v = fmaxf(v, 0.f);
      size_t off = (size_t)row * F + col;
      if (add1) v += bf2f(add1[off]);
      if (add2) v += bf2f(add2[off]);
      if (OUT_F32) Cf[off] = v; else Ch[off] = f2bf(v);
      if (C2) C2[off] = f2bf(v + pe3src[(size_t)row * 64 + (col & 63)]);
    }
  }
}

// ---------- small f32 GEMM (64x192x192 zg GEMM only) ----------
__global__ __launch_bounds__(256)
void gemm_kernel(const float* __restrict__ A, const float* __restrict__ B,
                 const float* __restrict__ bias, float* __restrict__ C,
                 int M, int K, int F) {
  __shared__ float Asm[16][65];
  __shared__ float Bsm[16][65];
  const int tid = threadIdx.x;
  const int tx = tid & 15, ty = tid >> 4;
  const int row0 = blockIdx.x * 64;
  const int col0 = blockIdx.y * 64;
  float acc[4][4];
#pragma unroll
  for (int i = 0; i < 4; i++)
#pragma unroll
    for (int j = 0; j < 4; j++) acc[i][j] = 0.f;

  for (int k0 = 0; k0 < K; k0 += 16) {
#pragma unroll
    for (int l = 0; l < 4; l++) {
      int idx = tid + l * 256;
      int m = idx >> 4, k = idx & 15;
      int r = row0 + m;
      Asm[k][m] = (r < M) ? A[(size_t)r * K + k0 + k] : 0.f;
    }
#pragma unroll
    for (int l = 0; l < 4; l++) {
      int idx = tid + l * 256;
      int k = idx >> 6, n = idx & 63;
      Bsm[k][n] = B[(size_t)(k0 + k) * F + col0 + n];
    }
    __syncthreads();
#pragma unroll
    for (int k = 0; k < 16; k++) {
      float a[4], b[4];
#pragma unroll
      for (int i = 0; i < 4; i++) a[i] = Asm[k][ty * 4 + i];
#pragma unroll
      for (int j = 0; j < 4; j++) b[j] = Bsm[k][tx * 4 + j];
#pragma unroll
      for (int i = 0; i < 4; i++)
#pragma unroll
        for (int j = 0; j < 4; j++) acc[i][j] += a[i] * b[j];
    }
    __syncthreads();
  }
#pragma unroll
  for (int i = 0; i < 4; i++) {
    int r = row0 + ty * 4 + i;
    if (r >= M) continue;
#pragma unroll
    for (int j = 0; j < 4; j++) {
      int c = col0 + tx * 4 + j;
      float v = acc[i][j];
      if (bias) v += bias[c];
      C[(size_t)r * F + c] = v;
    }
  }
}

// ---------- aggregations (bf16 in, f32 accumulate, bf16 out) ----------
template <int F>
__global__ void agg_mpnn_bf(const unsigned short* __restrict__ x, const int* __restrict__ rowstart,
                            const int* __restrict__ cnt, const int* __restrict__ srcs,
                            unsigned short* __restrict__ out) {
  constexpr int F8 = F / 8;
  int t = blockIdx.x * 256 + threadIdx.x;
  if (t >= N_NODES * F8) return;
  int i = t / F8, c = (t - i * F8) * 8;
  float a[8] = {0.f, 0.f, 0.f, 0.f, 0.f, 0.f, 0.f, 0.f};
  int e = rowstart[i], e1 = e + cnt[i];
  for (; e < e1; ++e) {
    int s = srcs[e];
    uint4 w = *(const uint4*)(x + (size_t)s * F + c);
    float f[8]; unpack8(w, f);
#pragma unroll
    for (int j = 0; j < 8; j++) a[j] += f[j];
  }
  *(uint4*)(out + (size_t)i * F + c) = pack8(a);
}

template <int F, bool RELU, bool HAS_BIAS>
__global__ void agg_gcn_bf(const unsigned short* __restrict__ x, const int* __restrict__ rowstart,
                           const int* __restrict__ cnt, const int* __restrict__ srcs,
                           const float* __restrict__ dinv, const float* __restrict__ bias,
                           unsigned short* __restrict__ out) {
  constexpr int F8 = F / 8;
  int t = blockIdx.x * 256 + threadIdx.x;
  if (t >= N_NODES * F8) return;
  int i = t / F8, c = (t - i * F8) * 8;
  float a[8] = {0.f, 0.f, 0.f, 0.f, 0.f, 0.f, 0.f, 0.f};
  int e = rowstart[i], e1 = e + cnt[i];
  for (; e < e1; ++e) {
    int s = srcs[e];
    float w = dinv[s];
    uint4 wv = *(const uint4*)(x + (size_t)s * F + c);
    float f[8]; unpack8(wv, f);
#pragma unroll
    for (int j = 0; j < 8; j++) a[j] += w * f[j];
  }
  float di = dinv[i];
  float sw = di * di;
  uint4 sv = *(const uint4*)(x + (size_t)i * F + c);
  float sf[8]; unpack8(sv, sf);
  float r[8];
#pragma unroll
  for (int j = 0; j < 8; j++) {
    float v = di * a[j] + sw * sf[j];
    if (HAS_BIAS) v += bias[c + j];
    if (RELU) v = fmaxf(v, 0.f);
    r[j] = v;
  }
  *(uint4*)(out + (size_t)i * F + c) = pack8(r);
}

// x2 aggregation: f32 input (32 cols), bf16 out
__global__ void agg_x2_k(const float* __restrict__ x, const int* __restrict__ rowstart,
                         const int* __restrict__ cnt, const int* __restrict__ srcs,
                         unsigned short* __restrict__ out) {
  int t = blockIdx.x * 256 + threadIdx.x;
  if (t >= N_NODES * 8) return;
  int i = t >> 3, c = (t & 7) * 4;
  float4 acc = make_float4(0.f, 0.f, 0.f, 0.f);
  int e = rowstart[i], e1 = e + cnt[i];
  for (; e < e1; ++e) {
    int s = srcs[e];
    float4 v = *(const float4*)(x + (size_t)s * 32 + c);
    acc.x += v.x; acc.y += v.y; acc.z += v.z; acc.w += v.w;
  }
  ushort4 o;
  o.x = f2bf(acc.x); o.y = f2bf(acc.y); o.z = f2bf(acc.z); o.w = f2bf(acc.w);
  *(ushort4*)(out + (size_t)i * 32 + c) = o;
}

// decoder GCN: source rows from 64-row f32 table zgW via batch.
// Fused dual output: out = z1_res (relu'd), out2 = z1_res + pe3.
__global__ void agg_gcn_dec_bf(const float* __restrict__ zgW, const int* __restrict__ rowstart,
                               const int* __restrict__ cnt, const int* __restrict__ srcs,
                               const int* __restrict__ batch, const float* __restrict__ dinv,
                               const float* __restrict__ bias, unsigned short* __restrict__ out,
                               const float* __restrict__ pe, unsigned short* __restrict__ out2) {
  int t = blockIdx.x * 256 + threadIdx.x;
  if (t >= N_NODES * 24) return;
  int i = t / 24, c = (t - i * 24) * 8;
  float a[8] = {0.f, 0.f, 0.f, 0.f, 0.f, 0.f, 0.f, 0.f};
  int e = rowstart[i], e1 = e + cnt[i];
  for (; e < e1; ++e) {
    int s = srcs[e];
    float w = dinv[s];
    const float* v = zgW + (size_t)batch[s] * 192 + c;
#pragma unroll
    for (int j = 0; j < 8; j++) a[j] += w * v[j];
  }
  float di = dinv[i];
  float sw = di * di;
  const float* sv = zgW + (size_t)batch[i] * 192 + c;
  float r[8];
#pragma unroll
  for (int j = 0; j < 8; j++)
    r[j] = fmaxf(di * a[j] + sw * sv[j] + bias[c + j], 0.f);
  *(uint4*)(out + (size_t)i * 192 + c) = pack8(r);
  // fused pe3 add: pe3[i, col] = pe[i, col & 63]; c is 8-aligned and 8|64 so
  // the 8-wide chunk never straddles a 64-boundary.
  const float* p = pe + (size_t)i * 64 + (c & 63);
  float r2[8];
#pragma unroll
  for (int j = 0; j < 8; j++) r2[j] = r[j] + p[j];
  *(uint4*)(out2 + (size_t)i * 192 + c) = pack8(r2);
}

// ---------- segment softmax (gate f32, z bf16) ----------
__global__ void init_gmax_k(unsigned* __restrict__ gmaxu) {
  int t = blockIdx.x * 256 + threadIdx.x;
  if (t < NGRAPH * 192) gmaxu[t] = 0x007FFFFFu;
}

__global__ void seg_max_k(const float* __restrict__ gate, const int* __restrict__ gstart,
                          unsigned* __restrict__ gmaxu) {
  int g = blockIdx.x, f = threadIdx.x;
  int lo = gstart[g], hi = gstart[g + 1];
  int len = hi - lo;
  if (len <= 0) return;
  int per = (len + gridDim.y - 1) / gridDim.y;
  int a = lo + blockIdx.y * per;
  int b = min(a + per, hi);
  if (a >= b) return;
  float m = -INFINITY;
  for (int i = a; i < b; i++) m = fmaxf(m, gate[(size_t)i * 192 + f]);
  atomicMax(&gmaxu[g * 192 + f], flip_f(m));
}

__global__ void seg_sum_k(const float* __restrict__ gate, const unsigned short* __restrict__ z,
                          const int* __restrict__ gstart, const unsigned* __restrict__ gmaxu,
                          float* __restrict__ esum, float* __restrict__ znum) {
  int g = blockIdx.x, f = threadIdx.x;
  int lo = gstart[g], hi = gstart[g + 1];
  int len = hi - lo;
  if (len <= 0) return;
  int per = (len + gridDim.y - 1) / gridDim.y;
  int a = lo + blockIdx.y * per;
  int b = min(a + per, hi);
  if (a >= b) return;
  float gm = unflip_f(gmaxu[g * 192 + f]);
  float se = 0.f, sz = 0.f;
  for (int i = a; i < b; i++) {
    float e = expf(gate[(size_t)i * 192 + f] - gm);
    se += e;
    sz += e * bf2f(z[(size_t)i * 192 + f]);
  }
  atomicAdd(&esum[g * 192 + f], se);
  atomicAdd(&znum[g * 192 + f], sz);
}

__global__ void zg_fin_k(const float* __restrict__ znum, const float* __restrict__ esum,
                         float* __restrict__ zg) {
  int t = blockIdx.x * 256 + threadIdx.x;
  if (t >= NGRAPH * 192) return;
  float es = esum[t];
  zg[t] = (es > 0.f) ? znum[t] / es : 0.f;
}

// ---------- launch ----------
extern "C" void kernel_launch(void* const* d_in, const int* in_sizes, int n_in,
                              void* d_out, int out_size, void* d_ws, size_t ws_size,
                              hipStream_t stream) {
  const float* x1 = (const float*)d_in[0];
  const float* x2 = (const float*)d_in[1];
  const float* pe = (const float*)d_in[2];
  const int* ei = (const int*)d_in[3];
  const int* src = ei;
  const int* dst = ei + N_EDGES;
  const int* batch = (const int*)d_in[4];
  const float* Wc  = (const float*)d_in[5];  const float* bc  = (const float*)d_in[6];
  const float* Wmf = (const float*)d_in[7];  const float* bmf = (const float*)d_in[8];
  const float* Wgf = (const float*)d_in[9];  const float* bgf = (const float*)d_in[10];
  const float* Wmc = (const float*)d_in[11]; const float* bmc = (const float*)d_in[12];
  const float* Wgc = (const float*)d_in[13]; const float* bgc = (const float*)d_in[14];
  const float* Wa1 = (const float*)d_in[15]; const float* ba1 = (const float*)d_in[16];
  const float* Wa2 = (const float*)d_in[17]; const float* ba2 = (const float*)d_in[18];
  const float* Wgd = (const float*)d_in[19]; const float* bgd = (const float*)d_in[20];
  const float* Wd1 = (const float*)d_in[21]; const float* bd1 = (const float*)d_in[22];
  const float* Wd2 = (const float*)d_in[23]; const float* bd2 = (const float*)d_in[24];
  const float* Wd3 = (const float*)d_in[25]; const float* bd3 = (const float*)d_in[26];
  float* out = (float*)d_out;

  char* base = (char*)d_ws;
  size_t woff = 0;
  auto walloc = [&](size_t bytes) -> void* {
    void* p = base + woff;
    woff = (woff + bytes + 255) & ~(size_t)255;
    return p;
  };
  unsigned short* P0h = (unsigned short*)walloc((size_t)N_NODES * 192 * 2); // x1_res -> z
  unsigned short* P1h = (unsigned short*)walloc((size_t)N_NODES * 256 * 2); // h/h1/a1/t1
  unsigned short* P2h = (unsigned short*)walloc((size_t)N_NODES * 192 * 2); // agg/t0/agg_b/agg_c
  unsigned short* P5a = (unsigned short*)walloc((size_t)N_NODES * 32 * 2);
  unsigned short* P5b = (unsigned short*)walloc((size_t)N_NODES * 64 * 2);
  unsigned short* P5c = (unsigned short*)walloc((size_t)N_NODES * 64 * 2);
  float* Pg   = (float*)walloc((size_t)N_NODES * 192 * 4);                  // gate (f32)
  float* dinv = (float*)walloc((size_t)N_NODES * 4);
  unsigned* gmaxu = (unsigned*)walloc((size_t)NGRAPH * 192 * 4);
  float* esum = (float*)walloc((size_t)NGRAPH * 192 * 4);
  float* znum = (float*)walloc((size_t)NGRAPH * 192 * 4);
  float* zg   = (float*)walloc((size_t)NGRAPH * 192 * 4);
  float* zgW  = (float*)walloc((size_t)NGRAPH * 192 * 4);
  int* cnt      = (int*)walloc((size_t)N_NODES * 4);
  int* rowstart = (int*)walloc((size_t)N_NODES * 4);
  int* cursor   = (int*)walloc((size_t)N_NODES * 4);
  int* srcs     = (int*)walloc((size_t)N_EDGES * 4);
  int* bsum     = (int*)walloc(512 * 4);
  int* gstart   = (int*)walloc(80 * 4);

  unsigned short* P3h = (unsigned short*)d_out;                            // lower half scratch
  unsigned short* P4h = (unsigned short*)((float*)d_out + (size_t)N_NODES * 192); // upper half

  const int TB = 256;
  hipMemsetAsync(cnt, 0, N_NODES * sizeof(int), stream);
  hipMemsetAsync(esum, 0, 2 * NGRAPH * 192 * sizeof(float), stream);

  hist_k<<<(N_EDGES + TB - 1) / TB, TB, 0, stream>>>(dst, cnt);
  dinv_k<<<(N_NODES + TB - 1) / TB, TB, 0, stream>>>(cnt, dinv);
  int nb = (N_NODES + 255) / 256;
  scan_block_k<<<nb, 256, 0, stream>>>(cnt, rowstart, bsum);
  scan_bsum_k<<<1, 512, 0, stream>>>(bsum, nb);
  scan_add_k<<<nb, 256, 0, stream>>>(rowstart, cursor, bsum);
  build_k<<<(N_EDGES + TB - 1) / TB, TB, 0, stream>>>(src, dst, cursor, srcs);
  graph_starts_k<<<1, 128, 0, stream>>>(batch, gstart);

  const int mb64 = (N_NODES + 63) / 64;
  const int ew24 = (N_NODES * 24 + TB - 1) / TB;
  const int ew8 = (N_NODES * 8 + TB - 1) / TB;

  // ---- encoder ----
  // fused: P0h = relu(x1@Wc+bc), P1h = P0h + pe3   (K=384, 4 K-tiles of 96, BN=192)
  gemm_t<float, 384, 96, 12, false><<<mb64, 256, 0, stream>>>(x1, Wc, bc, nullptr, nullptr, P0h, N_NODES, 192, 1, pe, P1h);
  agg_mpnn_bf<192><<<ew24, TB, 0, stream>>>(P1h, rowstart, cnt, srcs, P2h);
  gemm_t<unsigned short, 192, 192, 8, false><<<dim3(mb64, 2), 256, 0, stream>>>(P2h, Wmf, bmf, nullptr, nullptr, P1h, N_NODES, 256, 1, nullptr, nullptr);
  gemm_t<unsigned short, 256, 256, 6, false><<<dim3(mb64, 2), 256, 0, stream>>>(P1h, Wgf, nullptr, nullptr, nullptr, P3h, N_NODES, 192, 0, nullptr, nullptr);
  agg_gcn_bf<192, true, true><<<ew24, TB, 0, stream>>>(P3h, rowstart, cnt, srcs, dinv, bgf, P4h);
  agg_x2_k<<<ew8, TB, 0, stream>>>(x2, rowstart, cnt, srcs, P5a);
  gemm_t<unsigned short, 32, 32, 4, false><<<mb64, 256, 0, stream>>>(P5a, Wmc, bmc, nullptr, nullptr, P5b, N_NODES, 64, 1, nullptr, nullptr);
  agg_gcn_bf<64, false, false><<<ew8, TB, 0, stream>>>(P5b, rowstart, cnt, srcs, dinv, nullptr, P5c);
  // z = relu(cagg@Wgc + bgc) + h2 + x1_res  (in place over P0h)
  gemm_t<unsigned short, 64, 64, 6, false><<<dim3(mb64, 2), 256, 0, stream>>>(P5c, Wgc, bgc, P4h, P0h, P0h, N_NODES, 192, 1, nullptr, nullptr);

  // ---- attention aggregation ----
  gemm_t<unsigned short, 192, 192, 8, false><<<dim3(mb64, 2), 256, 0, stream>>>(P0h, Wa1, ba1, nullptr, nullptr, P1h, N_NODES, 256, 1, nullptr, nullptr);
  gemm_t<unsigned short, 256, 256, 6, true><<<dim3(mb64, 2), 256, 0, stream>>>(P1h, Wa2, ba2, nullptr, nullptr, Pg, N_NODES, 192, 0, nullptr, nullptr);
  init_gmax_k<<<(NGRAPH * 192 + TB - 1) / TB, TB, 0, stream>>>(gmaxu);
  dim3 sg(NGRAPH, 16);
  seg_max_k<<<sg, 192, 0, stream>>>(Pg, gstart, gmaxu);
  seg_sum_k<<<sg, 192, 0, stream>>>(Pg, P0h, gstart, gmaxu, esum, znum);
  zg_fin_k<<<(NGRAPH * 192 + TB - 1) / TB, TB, 0, stream>>>(znum, esum, zg);
  gemm_kernel<<<dim3(1, 3), 256, 0, stream>>>(zg, Wgd, nullptr, zgW, NGRAPH, 192, 192);

  // ---- decoder ----
  // fused: P4h = z1_res, P2h = z1_res + pe3
  agg_gcn_dec_bf<<<ew24, TB, 0, stream>>>(zgW, rowstart, cnt, srcs, batch, dinv, bgd, P4h, pe, P2h);
  agg_mpnn_bf<192><<<ew24, TB, 0, stream>>>(P2h, rowstart, cnt, srcs, P3h);
  gemm_t<unsigned short, 192, 192, 6, false><<<dim3(mb64, 2), 256, 0, stream>>>(P3h, Wd1, bd1, nullptr, nullptr, P1h, N_NODES, 192, 1, nullptr, nullptr);
  agg_mpnn_bf<192><<<ew24, TB, 0, stream>>>(P1h, rowstart, cnt, srcs, P2h);
  gemm_t<unsigned short, 192, 192, 6, false><<<dim3(mb64, 2), 256, 0, stream>>>(P2h, Wd2, bd2, P4h, nullptr, P3h, N_NODES, 192, 1, nullptr, nullptr);
  agg_mpnn_bf<192><<<ew24, TB, 0, stream>>>(P3h, rowstart, cnt, srcs, P2h);
  gemm_t<unsigned short, 192, 192, 8, true><<<dim3(mb64, 3), 256, 0, stream>>>(P2h, Wd3, bd3, nullptr, nullptr, out, N_NODES, 384, 1, nullptr, nullptr);
  (void)in_sizes; (void)n_in; (void)out_size; (void)ws_size;
}

// Round 4
// 1498.419 us; speedup vs baseline: 1.5847x; 1.5847x over previous
//
#include <hip/hip_runtime.h>
#include <math.h>

#define N_NODES 100000
#define N_EDGES 800000
#define NGRAPH  64

typedef __attribute__((ext_vector_type(8))) __bf16 bf16x8;
typedef __attribute__((ext_vector_type(4))) float f32x4;

// ---------- helpers ----------
static __device__ __forceinline__ unsigned flip_f(float x) {
  unsigned u = __float_as_uint(x);
  return u ^ ((u & 0x80000000u) ? 0xFFFFFFFFu : 0x80000000u);
}
static __device__ __forceinline__ float unflip_f(unsigned m) {
  unsigned u = m ^ ((m & 0x80000000u) ? 0x80000000u : 0xFFFFFFFFu);
  return __uint_as_float(u);
}
static __device__ __forceinline__ unsigned short f2bf(float x) {
  unsigned u = __float_as_uint(x);
  u += 0x7fffu + ((u >> 16) & 1u);   // RNE
  return (unsigned short)(u >> 16);
}
static __device__ __forceinline__ unsigned pk2(float a, float b) {
  return (unsigned)f2bf(a) | ((unsigned)f2bf(b) << 16);
}
static __device__ __forceinline__ float bf2f(unsigned short h) {
  return __uint_as_float((unsigned)h << 16);
}
static __device__ __forceinline__ void unpack8(uint4 w, float* f) {
  f[0] = __uint_as_float(w.x << 16); f[1] = __uint_as_float(w.x & 0xFFFF0000u);
  f[2] = __uint_as_float(w.y << 16); f[3] = __uint_as_float(w.y & 0xFFFF0000u);
  f[4] = __uint_as_float(w.z << 16); f[5] = __uint_as_float(w.z & 0xFFFF0000u);
  f[6] = __uint_as_float(w.w << 16); f[7] = __uint_as_float(w.w & 0xFFFF0000u);
}
static __device__ __forceinline__ uint4 pack8(const float* f) {
  uint4 w;
  w.x = pk2(f[0], f[1]); w.y = pk2(f[2], f[3]);
  w.z = pk2(f[4], f[5]); w.w = pk2(f[6], f[7]);
  return w;
}

// ---------- CSR build ----------
__global__ void hist_k(const int* __restrict__ dst, int* __restrict__ cnt) {
  int e = blockIdx.x * 256 + threadIdx.x;
  if (e < N_EDGES) atomicAdd(&cnt[dst[e]], 1);
}

__global__ void dinv_k(const int* __restrict__ cnt, float* __restrict__ dinv) {
  int i = blockIdx.x * 256 + threadIdx.x;
  if (i < N_NODES) dinv[i] = rsqrtf((float)cnt[i] + 1.0f);
}

__global__ void scan_block_k(const int* __restrict__ cnt, int* __restrict__ rs,
                             int* __restrict__ bsum) {
  __shared__ int s[256];
  int t = threadIdx.x, i = blockIdx.x * 256 + t;
  int v = (i < N_NODES) ? cnt[i] : 0;
  s[t] = v; __syncthreads();
  for (int off = 1; off < 256; off <<= 1) {
    int a = (t >= off) ? s[t - off] : 0;
    __syncthreads();
    s[t] += a;
    __syncthreads();
  }
  if (i < N_NODES) rs[i] = s[t] - v;
  if (t == 255) bsum[blockIdx.x] = s[255];
}

__global__ void scan_bsum_k(int* __restrict__ bsum, int nb) {
  __shared__ int s[512];
  int t = threadIdx.x;
  int v = (t < nb) ? bsum[t] : 0;
  s[t] = v; __syncthreads();
  for (int off = 1; off < 512; off <<= 1) {
    int a = (t >= off) ? s[t - off] : 0;
    __syncthreads();
    s[t] += a;
    __syncthreads();
  }
  if (t < nb) bsum[t] = s[t] - v;
}

__global__ void scan_add_k(int* __restrict__ rs, int* __restrict__ cursor,
                           const int* __restrict__ bsum) {
  int i = blockIdx.x * 256 + threadIdx.x;
  if (i < N_NODES) {
    int r = rs[i] + bsum[i >> 8];
    rs[i] = r;
    cursor[i] = r;
  }
}

__global__ void build_k(const int* __restrict__ src, const int* __restrict__ dst,
                        int* __restrict__ cursor, int* __restrict__ srcs) {
  int e = blockIdx.x * 256 + threadIdx.x;
  if (e < N_EDGES) {
    int d = dst[e];
    int p = atomicAdd(&cursor[d], 1);
    srcs[p] = src[e];
  }
}

__global__ void graph_starts_k(const int* __restrict__ batch, int* __restrict__ gstart) {
  int g = threadIdx.x;
  if (g > NGRAPH) return;
  if (g == NGRAPH) { gstart[NGRAPH] = N_NODES; return; }
  int lo = 0, hi = N_NODES;
  while (lo < hi) {
    int mid = (lo + hi) >> 1;
    if (batch[mid] < g) lo = mid + 1; else hi = mid;
  }
  gstart[g] = lo;
}

// ---------- MFMA bf16 GEMM: B LDS-resident (coalesced staging), A direct-to-reg ----------
// Block = 64 rows x BN cols (BN = 16*NT), 4 waves, wave w owns rows [w*16, w*16+16).
// Per K-tile: issue A fragment loads (global->reg) -> stage B (f32->bf16, lanes map
// to ADJACENT COLUMNS: 32-lane x 4B = 128B coalesced segments) -> barrier -> pure
// MFMA compute with zero barriers. KTILES==1 for all but Wc.
template <typename AT, int K, int KT, int NT, bool OUT_F32>
__global__ __launch_bounds__(256, 2)
void gemm_t(const AT* __restrict__ A, const float* __restrict__ B,
            const float* __restrict__ bias,
            const unsigned short* __restrict__ add1,
            const unsigned short* __restrict__ add2,
            void* __restrict__ Cv, int M, int F, int relu,
            const float* __restrict__ pe3src, unsigned short* __restrict__ C2) {
  constexpr int BN = 16 * NT;
  constexpr int KTILES = K / KT;
  constexpr int NSTEP = KT / 32;     // 32-k steps per tile
  constexpr int KOCTS = KT / 8;      // 8-k octs per tile
  constexpr int STK = KT + 8;        // LDS row stride: STK/2 mod 8 == 4 -> free 2-way alias
  __shared__ unsigned short Bs[BN * STK];
  const int tid = threadIdx.x;
  const int wave = tid >> 6, lane = tid & 63;
  const int quad = lane >> 4, l16 = lane & 15;
  const int row0 = blockIdx.x * 64;
  const int col0 = blockIdx.y * BN;
  const int arow = row0 + wave * 16 + l16;
  const bool aok = arow < M;
  const int nsub = tid & 31;         // column within 32-group (coalesced over lanes)
  const int koct = tid >> 5;         // 0..7

  f32x4 acc[NT];
#pragma unroll
  for (int j = 0; j < NT; j++) acc[j] = (f32x4){0.f, 0.f, 0.f, 0.f};

#pragma unroll
  for (int kt = 0; kt < KTILES; ++kt) {
    if (kt) __syncthreads();  // protect LDS before overwrite (Wc only)

    // ---- A fragments for this K-tile: direct global->reg, issued first ----
    float4 av[sizeof(AT) == 4 ? 2 * NSTEP : 1];
    uint4 ah[sizeof(AT) == 4 ? 1 : NSTEP];
    if constexpr (sizeof(AT) == 4) {
      const float* ap = (const float*)A + (size_t)arow * K + kt * KT + quad * 8;
#pragma unroll
      for (int s = 0; s < NSTEP; s++) {
        av[2 * s] = aok ? *(const float4*)(ap + s * 32) : make_float4(0.f, 0.f, 0.f, 0.f);
        av[2 * s + 1] = aok ? *(const float4*)(ap + s * 32 + 4) : make_float4(0.f, 0.f, 0.f, 0.f);
      }
    } else {
      const unsigned short* ap = (const unsigned short*)A + (size_t)arow * K + kt * KT + quad * 8;
#pragma unroll
      for (int s = 0; s < NSTEP; s++)
        ah[s] = aok ? *(const uint4*)(ap + s * 32) : make_uint4(0, 0, 0, 0);
    }

    // ---- stage B tile (coalesced: adjacent lanes -> adjacent columns) ----
#pragma unroll
    for (int ob = 0; ob < KOCTS; ob += 8) {
      int oct = ob + koct;
      if (oct < KOCTS) {
#pragma unroll
        for (int nc = 0; nc < BN; nc += 32) {
          int n = nc + nsub;
          const float* bp = B + (size_t)(kt * KT + oct * 8) * F + col0 + n;
          uint4 w;
          w.x = pk2(bp[0], bp[(size_t)1 * F]);
          w.y = pk2(bp[(size_t)2 * F], bp[(size_t)3 * F]);
          w.z = pk2(bp[(size_t)4 * F], bp[(size_t)5 * F]);
          w.w = pk2(bp[(size_t)6 * F], bp[(size_t)7 * F]);
          *(uint4*)&Bs[n * STK + oct * 8] = w;
        }
      }
    }
    __syncthreads();

    // ---- compute: zero barriers ----
#pragma unroll
    for (int s = 0; s < NSTEP; ++s) {
      bf16x8 afr;
      if constexpr (sizeof(AT) == 4) {
        uint4 t;
        t.x = pk2(av[2 * s].x, av[2 * s].y);
        t.y = pk2(av[2 * s].z, av[2 * s].w);
        t.z = pk2(av[2 * s + 1].x, av[2 * s + 1].y);
        t.w = pk2(av[2 * s + 1].z, av[2 * s + 1].w);
        afr = *(bf16x8*)&t;
      } else {
        afr = *(bf16x8*)&ah[s];
      }
#pragma unroll
      for (int nt = 0; nt < NT; nt++) {
        bf16x8 bfr = *(const bf16x8*)&Bs[(nt * 16 + l16) * STK + s * 32 + quad * 8];
        acc[nt] = __builtin_amdgcn_mfma_f32_16x16x32_bf16(afr, bfr, acc[nt], 0, 0, 0);
      }
    }
  }

  // ---- epilogue ----
  float* Cf = (float*)Cv;
  unsigned short* Ch = (unsigned short*)Cv;
#pragma unroll
  for (int r = 0; r < 4; r++) {
    int row = row0 + wave * 16 + quad * 4 + r;
    if (row >= M) continue;
#pragma unroll
    for (int nt = 0; nt < NT; nt++) {
      int col = col0 + nt * 16 + l16;
      float v = acc[nt][r];
      if (bias) v += bias[col];
      if (relu) v = fmaxf(v, 0.f);
      size_t off = (size_t)row * F + col;
      if (add1) v += bf2f(add1[off]);
      if (add2) v += bf2f(add2[off]);
      if (OUT_F32) Cf[off] = v; else Ch[off] = f2bf(v);
      if (C2) C2[off] = f2bf(v + pe3src[(size_t)row * 64 + (col & 63)]);
    }
  }
}

// ---------- small f32 GEMM (64x192x192 zg GEMM only) ----------
__global__ __launch_bounds__(256)
void gemm_kernel(const float* __restrict__ A, const float* __restrict__ B,
                 const float* __restrict__ bias, float* __restrict__ C,
                 int M, int K, int F) {
  __shared__ float Asm[16][65];
  __shared__ float Bsm[16][65];
  const int tid = threadIdx.x;
  const int tx = tid & 15, ty = tid >> 4;
  const int row0 = blockIdx.x * 64;
  const int col0 = blockIdx.y * 64;
  float acc[4][4];
#pragma unroll
  for (int i = 0; i < 4; i++)
#pragma unroll
    for (int j = 0; j < 4; j++) acc[i][j] = 0.f;

  for (int k0 = 0; k0 < K; k0 += 16) {
#pragma unroll
    for (int l = 0; l < 4; l++) {
      int idx = tid + l * 256;
      int m = idx >> 4, k = idx & 15;
      int r = row0 + m;
      Asm[k][m] = (r < M) ? A[(size_t)r * K + k0 + k] : 0.f;
    }
#pragma unroll
    for (int l = 0; l < 4; l++) {
      int idx = tid + l * 256;
      int k = idx >> 6, n = idx & 63;
      Bsm[k][n] = B[(size_t)(k0 + k) * F + col0 + n];
    }
    __syncthreads();
#pragma unroll
    for (int k = 0; k < 16; k++) {
      float a[4], b[4];
#pragma unroll
      for (int i = 0; i < 4; i++) a[i] = Asm[k][ty * 4 + i];
#pragma unroll
      for (int j = 0; j < 4; j++) b[j] = Bsm[k][tx * 4 + j];
#pragma unroll
      for (int i = 0; i < 4; i++)
#pragma unroll
        for (int j = 0; j < 4; j++) acc[i][j] += a[i] * b[j];
    }
    __syncthreads();
  }
#pragma unroll
  for (int i = 0; i < 4; i++) {
    int r = row0 + ty * 4 + i;
    if (r >= M) continue;
#pragma unroll
    for (int j = 0; j < 4; j++) {
      int c = col0 + tx * 4 + j;
      float v = acc[i][j];
      if (bias) v += bias[c];
      C[(size_t)r * F + c] = v;
    }
  }
}

// ---------- aggregations (bf16 in, f32 accumulate, bf16 out) ----------
template <int F>
__global__ void agg_mpnn_bf(const unsigned short* __restrict__ x, const int* __restrict__ rowstart,
                            const int* __restrict__ cnt, const int* __restrict__ srcs,
                            unsigned short* __restrict__ out) {
  constexpr int F8 = F / 8;
  int t = blockIdx.x * 256 + threadIdx.x;
  if (t >= N_NODES * F8) return;
  int i = t / F8, c = (t - i * F8) * 8;
  float a[8] = {0.f, 0.f, 0.f, 0.f, 0.f, 0.f, 0.f, 0.f};
  int e = rowstart[i], e1 = e + cnt[i];
  for (; e < e1; ++e) {
    int s = srcs[e];
    uint4 w = *(const uint4*)(x + (size_t)s * F + c);
    float f[8]; unpack8(w, f);
#pragma unroll
    for (int j = 0; j < 8; j++) a[j] += f[j];
  }
  *(uint4*)(out + (size_t)i * F + c) = pack8(a);
}

template <int F, bool RELU, bool HAS_BIAS>
__global__ void agg_gcn_bf(const unsigned short* __restrict__ x, const int* __restrict__ rowstart,
                           const int* __restrict__ cnt, const int* __restrict__ srcs,
                           const float* __restrict__ dinv, const float* __restrict__ bias,
                           unsigned short* __restrict__ out) {
  constexpr int F8 = F / 8;
  int t = blockIdx.x * 256 + threadIdx.x;
  if (t >= N_NODES * F8) return;
  int i = t / F8, c = (t - i * F8) * 8;
  float a[8] = {0.f, 0.f, 0.f, 0.f, 0.f, 0.f, 0.f, 0.f};
  int e = rowstart[i], e1 = e + cnt[i];
  for (; e < e1; ++e) {
    int s = srcs[e];
    float w = dinv[s];
    uint4 wv = *(const uint4*)(x + (size_t)s * F + c);
    float f[8]; unpack8(wv, f);
#pragma unroll
    for (int j = 0; j < 8; j++) a[j] += w * f[j];
  }
  float di = dinv[i];
  float sw = di * di;
  uint4 sv = *(const uint4*)(x + (size_t)i * F + c);
  float sf[8]; unpack8(sv, sf);
  float r[8];
#pragma unroll
  for (int j = 0; j < 8; j++) {
    float v = di * a[j] + sw * sf[j];
    if (HAS_BIAS) v += bias[c + j];
    if (RELU) v = fmaxf(v, 0.f);
    r[j] = v;
  }
  *(uint4*)(out + (size_t)i * F + c) = pack8(r);
}

// x2 aggregation: f32 input (32 cols), bf16 out
__global__ void agg_x2_k(const float* __restrict__ x, const int* __restrict__ rowstart,
                         const int* __restrict__ cnt, const int* __restrict__ srcs,
                         unsigned short* __restrict__ out) {
  int t = blockIdx.x * 256 + threadIdx.x;
  if (t >= N_NODES * 8) return;
  int i = t >> 3, c = (t & 7) * 4;
  float4 acc = make_float4(0.f, 0.f, 0.f, 0.f);
  int e = rowstart[i], e1 = e + cnt[i];
  for (; e < e1; ++e) {
    int s = srcs[e];
    float4 v = *(const float4*)(x + (size_t)s * 32 + c);
    acc.x += v.x; acc.y += v.y; acc.z += v.z; acc.w += v.w;
  }
  ushort4 o;
  o.x = f2bf(acc.x); o.y = f2bf(acc.y); o.z = f2bf(acc.z); o.w = f2bf(acc.w);
  *(ushort4*)(out + (size_t)i * 32 + c) = o;
}

// decoder GCN: source rows from 64-row f32 table zgW via batch.
// Fused dual output: out = z1_res (relu'd), out2 = z1_res + pe3.
__global__ void agg_gcn_dec_bf(const float* __restrict__ zgW, const int* __restrict__ rowstart,
                               const int* __restrict__ cnt, const int* __restrict__ srcs,
                               const int* __restrict__ batch, const float* __restrict__ dinv,
                               const float* __restrict__ bias, unsigned short* __restrict__ out,
                               const float* __restrict__ pe, unsigned short* __restrict__ out2) {
  int t = blockIdx.x * 256 + threadIdx.x;
  if (t >= N_NODES * 24) return;
  int i = t / 24, c = (t - i * 24) * 8;
  float a[8] = {0.f, 0.f, 0.f, 0.f, 0.f, 0.f, 0.f, 0.f};
  int e = rowstart[i], e1 = e + cnt[i];
  for (; e < e1; ++e) {
    int s = srcs[e];
    float w = dinv[s];
    const float* v = zgW + (size_t)batch[s] * 192 + c;
#pragma unroll
    for (int j = 0; j < 8; j++) a[j] += w * v[j];
  }
  float di = dinv[i];
  float sw = di * di;
  const float* sv = zgW + (size_t)batch[i] * 192 + c;
  float r[8];
#pragma unroll
  for (int j = 0; j < 8; j++)
    r[j] = fmaxf(di * a[j] + sw * sv[j] + bias[c + j], 0.f);
  *(uint4*)(out + (size_t)i * 192 + c) = pack8(r);
  // fused pe3 add: pe3[i, col] = pe[i, col & 63]; c is 8-aligned and 8|64 so
  // the 8-wide chunk never straddles a 64-boundary.
  const float* p = pe + (size_t)i * 64 + (c & 63);
  float r2[8];
#pragma unroll
  for (int j = 0; j < 8; j++) r2[j] = r[j] + p[j];
  *(uint4*)(out2 + (size_t)i * 192 + c) = pack8(r2);
}

// ---------- segment softmax (gate f32, z bf16) ----------
__global__ void init_gmax_k(unsigned* __restrict__ gmaxu) {
  int t = blockIdx.x * 256 + threadIdx.x;
  if (t < NGRAPH * 192) gmaxu[t] = 0x007FFFFFu;
}

__global__ void seg_max_k(const float* __restrict__ gate, const int* __restrict__ gstart,
                          unsigned* __restrict__ gmaxu) {
  int g = blockIdx.x, f = threadIdx.x;
  int lo = gstart[g], hi = gstart[g + 1];
  int len = hi - lo;
  if (len <= 0) return;
  int per = (len + gridDim.y - 1) / gridDim.y;
  int a = lo + blockIdx.y * per;
  int b = min(a + per, hi);
  if (a >= b) return;
  float m = -INFINITY;
  for (int i = a; i < b; i++) m = fmaxf(m, gate[(size_t)i * 192 + f]);
  atomicMax(&gmaxu[g * 192 + f], flip_f(m));
}

__global__ void seg_sum_k(const float* __restrict__ gate, const unsigned short* __restrict__ z,
                          const int* __restrict__ gstart, const unsigned* __restrict__ gmaxu,
                          float* __restrict__ esum, float* __restrict__ znum) {
  int g = blockIdx.x, f = threadIdx.x;
  int lo = gstart[g], hi = gstart[g + 1];
  int len = hi - lo;
  if (len <= 0) return;
  int per = (len + gridDim.y - 1) / gridDim.y;
  int a = lo + blockIdx.y * per;
  int b = min(a + per, hi);
  if (a >= b) return;
  float gm = unflip_f(gmaxu[g * 192 + f]);
  float se = 0.f, sz = 0.f;
  for (int i = a; i < b; i++) {
    float e = expf(gate[(size_t)i * 192 + f] - gm);
    se += e;
    sz += e * bf2f(z[(size_t)i * 192 + f]);
  }
  atomicAdd(&esum[g * 192 + f], se);
  atomicAdd(&znum[g * 192 + f], sz);
}

__global__ void zg_fin_k(const float* __restrict__ znum, const float* __restrict__ esum,
                         float* __restrict__ zg) {
  int t = blockIdx.x * 256 + threadIdx.x;
  if (t >= NGRAPH * 192) return;
  float es = esum[t];
  zg[t] = (es > 0.f) ? znum[t] / es : 0.f;
}

// ---------- launch ----------
extern "C" void kernel_launch(void* const* d_in, const int* in_sizes, int n_in,
                              void* d_out, int out_size, void* d_ws, size_t ws_size,
                              hipStream_t stream) {
  const float* x1 = (const float*)d_in[0];
  const float* x2 = (const float*)d_in[1];
  const float* pe = (const float*)d_in[2];
  const int* ei = (const int*)d_in[3];
  const int* src = ei;
  const int* dst = ei + N_EDGES;
  const int* batch = (const int*)d_in[4];
  const float* Wc  = (const float*)d_in[5];  const float* bc  = (const float*)d_in[6];
  const float* Wmf = (const float*)d_in[7];  const float* bmf = (const float*)d_in[8];
  const float* Wgf = (const float*)d_in[9];  const float* bgf = (const float*)d_in[10];
  const float* Wmc = (const float*)d_in[11]; const float* bmc = (const float*)d_in[12];
  const float* Wgc = (const float*)d_in[13]; const float* bgc = (const float*)d_in[14];
  const float* Wa1 = (const float*)d_in[15]; const float* ba1 = (const float*)d_in[16];
  const float* Wa2 = (const float*)d_in[17]; const float* ba2 = (const float*)d_in[18];
  const float* Wgd = (const float*)d_in[19]; const float* bgd = (const float*)d_in[20];
  const float* Wd1 = (const float*)d_in[21]; const float* bd1 = (const float*)d_in[22];
  const float* Wd2 = (const float*)d_in[23]; const float* bd2 = (const float*)d_in[24];
  const float* Wd3 = (const float*)d_in[25]; const float* bd3 = (const float*)d_in[26];
  float* out = (float*)d_out;

  char* base = (char*)d_ws;
  size_t woff = 0;
  auto walloc = [&](size_t bytes) -> void* {
    void* p = base + woff;
    woff = (woff + bytes + 255) & ~(size_t)255;
    return p;
  };
  unsigned short* P0h = (unsigned short*)walloc((size_t)N_NODES * 192 * 2); // x1_res -> z
  unsigned short* P1h = (unsigned short*)walloc((size_t)N_NODES * 256 * 2); // h/h1/a1/t1
  unsigned short* P2h = (unsigned short*)walloc((size_t)N_NODES * 192 * 2); // agg/t0/agg_b/agg_c
  unsigned short* P5a = (unsigned short*)walloc((size_t)N_NODES * 32 * 2);
  unsigned short* P5b = (unsigned short*)walloc((size_t)N_NODES * 64 * 2);
  unsigned short* P5c = (unsigned short*)walloc((size_t)N_NODES * 64 * 2);
  float* Pg   = (float*)walloc((size_t)N_NODES * 192 * 4);                  // gate (f32)
  float* dinv = (float*)walloc((size_t)N_NODES * 4);
  unsigned* gmaxu = (unsigned*)walloc((size_t)NGRAPH * 192 * 4);
  float* esum = (float*)walloc((size_t)NGRAPH * 192 * 4);
  float* znum = (float*)walloc((size_t)NGRAPH * 192 * 4);
  float* zg   = (float*)walloc((size_t)NGRAPH * 192 * 4);
  float* zgW  = (float*)walloc((size_t)NGRAPH * 192 * 4);
  int* cnt      = (int*)walloc((size_t)N_NODES * 4);
  int* rowstart = (int*)walloc((size_t)N_NODES * 4);
  int* cursor   = (int*)walloc((size_t)N_NODES * 4);
  int* srcs     = (int*)walloc((size_t)N_EDGES * 4);
  int* bsum     = (int*)walloc(512 * 4);
  int* gstart   = (int*)walloc(80 * 4);

  unsigned short* P3h = (unsigned short*)d_out;                            // lower half scratch
  unsigned short* P4h = (unsigned short*)((float*)d_out + (size_t)N_NODES * 192); // upper half

  const int TB = 256;
  hipMemsetAsync(cnt, 0, N_NODES * sizeof(int), stream);
  hipMemsetAsync(esum, 0, 2 * NGRAPH * 192 * sizeof(float), stream);

  hist_k<<<(N_EDGES + TB - 1) / TB, TB, 0, stream>>>(dst, cnt);
  dinv_k<<<(N_NODES + TB - 1) / TB, TB, 0, stream>>>(cnt, dinv);
  int nb = (N_NODES + 255) / 256;
  scan_block_k<<<nb, 256, 0, stream>>>(cnt, rowstart, bsum);
  scan_bsum_k<<<1, 512, 0, stream>>>(bsum, nb);
  scan_add_k<<<nb, 256, 0, stream>>>(rowstart, cursor, bsum);
  build_k<<<(N_EDGES + TB - 1) / TB, TB, 0, stream>>>(src, dst, cursor, srcs);
  graph_starts_k<<<1, 128, 0, stream>>>(batch, gstart);

  const int mb64 = (N_NODES + 63) / 64;
  const int ew24 = (N_NODES * 24 + TB - 1) / TB;
  const int ew8 = (N_NODES * 8 + TB - 1) / TB;

  // ---- encoder ----
  // fused: P0h = relu(x1@Wc+bc), P1h = P0h + pe3   (K=384, 3 K-tiles of 128, BN=192)
  gemm_t<float, 384, 128, 12, false><<<mb64, 256, 0, stream>>>(x1, Wc, bc, nullptr, nullptr, P0h, N_NODES, 192, 1, pe, P1h);
  agg_mpnn_bf<192><<<ew24, TB, 0, stream>>>(P1h, rowstart, cnt, srcs, P2h);
  gemm_t<unsigned short, 192, 192, 8, false><<<dim3(mb64, 2), 256, 0, stream>>>(P2h, Wmf, bmf, nullptr, nullptr, P1h, N_NODES, 256, 1, nullptr, nullptr);
  gemm_t<unsigned short, 256, 256, 6, false><<<dim3(mb64, 2), 256, 0, stream>>>(P1h, Wgf, nullptr, nullptr, nullptr, P3h, N_NODES, 192, 0, nullptr, nullptr);
  agg_gcn_bf<192, true, true><<<ew24, TB, 0, stream>>>(P3h, rowstart, cnt, srcs, dinv, bgf, P4h);
  agg_x2_k<<<ew8, TB, 0, stream>>>(x2, rowstart, cnt, srcs, P5a);
  gemm_t<unsigned short, 32, 32, 4, false><<<mb64, 256, 0, stream>>>(P5a, Wmc, bmc, nullptr, nullptr, P5b, N_NODES, 64, 1, nullptr, nullptr);
  agg_gcn_bf<64, false, false><<<ew8, TB, 0, stream>>>(P5b, rowstart, cnt, srcs, dinv, nullptr, P5c);
  // z = relu(cagg@Wgc + bgc) + h2 + x1_res  (in place over P0h)
  gemm_t<unsigned short, 64, 64, 6, false><<<dim3(mb64, 2), 256, 0, stream>>>(P5c, Wgc, bgc, P4h, P0h, P0h, N_NODES, 192, 1, nullptr, nullptr);

  // ---- attention aggregation ----
  gemm_t<unsigned short, 192, 192, 8, false><<<dim3(mb64, 2), 256, 0, stream>>>(P0h, Wa1, ba1, nullptr, nullptr, P1h, N_NODES, 256, 1, nullptr, nullptr);
  gemm_t<unsigned short, 256, 256, 6, true><<<dim3(mb64, 2), 256, 0, stream>>>(P1h, Wa2, ba2, nullptr, nullptr, Pg, N_NODES, 192, 0, nullptr, nullptr);
  init_gmax_k<<<(NGRAPH * 192 + TB - 1) / TB, TB, 0, stream>>>(gmaxu);
  dim3 sg(NGRAPH, 16);
  seg_max_k<<<sg, 192, 0, stream>>>(Pg, gstart, gmaxu);
  seg_sum_k<<<sg, 192, 0, stream>>>(Pg, P0h, gstart, gmaxu, esum, znum);
  zg_fin_k<<<(NGRAPH * 192 + TB - 1) / TB, TB, 0, stream>>>(znum, esum, zg);
  gemm_kernel<<<dim3(1, 3), 256, 0, stream>>>(zg, Wgd, nullptr, zgW, NGRAPH, 192, 192);

  // ---- decoder ----
  // fused: P4h = z1_res, P2h = z1_res + pe3
  agg_gcn_dec_bf<<<ew24, TB, 0, stream>>>(zgW, rowstart, cnt, srcs, batch, dinv, bgd, P4h, pe, P2h);
  agg_mpnn_bf<192><<<ew24, TB, 0, stream>>>(P2h, rowstart, cnt, srcs, P3h);
  gemm_t<unsigned short, 192, 192, 6, false><<<dim3(mb64, 2), 256, 0, stream>>>(P3h, Wd1, bd1, nullptr, nullptr, P1h, N_NODES, 192, 1, nullptr, nullptr);
  agg_mpnn_bf<192><<<ew24, TB, 0, stream>>>(P1h, rowstart, cnt, srcs, P2h);
  gemm_t<unsigned short, 192, 192, 6, false><<<dim3(mb64, 2), 256, 0, stream>>>(P2h, Wd2, bd2, P4h, nullptr, P3h, N_NODES, 192, 1, nullptr, nullptr);
  agg_mpnn_bf<192><<<ew24, TB, 0, stream>>>(P3h, rowstart, cnt, srcs, P2h);
  gemm_t<unsigned short, 192, 192, 8, true><<<dim3(mb64, 3), 256, 0, stream>>>(P2h, Wd3, bd3, nullptr, nullptr, out, N_NODES, 384, 1, nullptr, nullptr);
  (void)in_sizes; (void)n_in; (void)out_size; (void)ws_size;
}

// Round 5
// 1426.248 us; speedup vs baseline: 1.6649x; 1.0506x over previous
//
#include <hip/hip_runtime.h>
#include <math.h>

#define N_NODES 100000
#define N_EDGES 800000
#define NGRAPH  64

typedef __attribute__((ext_vector_type(8))) __bf16 bf16x8;
typedef __attribute__((ext_vector_type(4))) float f32x4;

// ---------- helpers ----------
static __device__ __forceinline__ unsigned flip_f(float x) {
  unsigned u = __float_as_uint(x);
  return u ^ ((u & 0x80000000u) ? 0xFFFFFFFFu : 0x80000000u);
}
static __device__ __forceinline__ float unflip_f(unsigned m) {
  unsigned u = m ^ ((m & 0x80000000u) ? 0x80000000u : 0xFFFFFFFFu);
  return __uint_as_float(u);
}
static __device__ __forceinline__ unsigned short f2bf(float x) {
  unsigned u = __float_as_uint(x);
  u += 0x7fffu + ((u >> 16) & 1u);   // RNE
  return (unsigned short)(u >> 16);
}
static __device__ __forceinline__ unsigned pk2(float a, float b) {
  return (unsigned)f2bf(a) | ((unsigned)f2bf(b) << 16);
}
static __device__ __forceinline__ float bf2f(unsigned short h) {
  return __uint_as_float((unsigned)h << 16);
}
static __device__ __forceinline__ void unpack8(uint4 w, float* f) {
  f[0] = __uint_as_float(w.x << 16); f[1] = __uint_as_float(w.x & 0xFFFF0000u);
  f[2] = __uint_as_float(w.y << 16); f[3] = __uint_as_float(w.y & 0xFFFF0000u);
  f[4] = __uint_as_float(w.z << 16); f[5] = __uint_as_float(w.z & 0xFFFF0000u);
  f[6] = __uint_as_float(w.w << 16); f[7] = __uint_as_float(w.w & 0xFFFF0000u);
}
static __device__ __forceinline__ uint4 pack8(const float* f) {
  uint4 w;
  w.x = pk2(f[0], f[1]); w.y = pk2(f[2], f[3]);
  w.z = pk2(f[4], f[5]); w.w = pk2(f[6], f[7]);
  return w;
}

// ---------- weight prep: f32 [K][F] -> bf16 [F][K] (transpose + convert), 10 jobs ----------
struct WJobs {
  const float* src[10];
  int K[10];
  int F[10];
  int eoff[10];   // element offset into dst
  int bend[10];   // exclusive cumulative block end
};

__global__ void wconv_k(WJobs jb, unsigned short* __restrict__ dst) {
  int b = blockIdx.x;
  int j = 0;
#pragma unroll
  for (int t = 0; t < 10; t++)
    if (b >= jb.bend[t]) j = t + 1;
  int bstart = j ? jb.bend[j - 1] : 0;
  int local = (b - bstart) * 256 + threadIdx.x;
  int K = jb.K[j], F = jb.F[j];
  if (local >= K * F) return;
  int n = local / K;
  int k = local - n * K;
  dst[jb.eoff[j] + local] = f2bf(jb.src[j][(size_t)k * F + n]);
}

// ---------- CSR build ----------
__global__ void hist_k(const int* __restrict__ dst, int* __restrict__ cnt) {
  int e = blockIdx.x * 256 + threadIdx.x;
  if (e < N_EDGES) atomicAdd(&cnt[dst[e]], 1);
}

__global__ void dinv_k(const int* __restrict__ cnt, float* __restrict__ dinv) {
  int i = blockIdx.x * 256 + threadIdx.x;
  if (i < N_NODES) dinv[i] = rsqrtf((float)cnt[i] + 1.0f);
}

__global__ void scan_block_k(const int* __restrict__ cnt, int* __restrict__ rs,
                             int* __restrict__ bsum) {
  __shared__ int s[256];
  int t = threadIdx.x, i = blockIdx.x * 256 + t;
  int v = (i < N_NODES) ? cnt[i] : 0;
  s[t] = v; __syncthreads();
  for (int off = 1; off < 256; off <<= 1) {
    int a = (t >= off) ? s[t - off] : 0;
    __syncthreads();
    s[t] += a;
    __syncthreads();
  }
  if (i < N_NODES) rs[i] = s[t] - v;
  if (t == 255) bsum[blockIdx.x] = s[255];
}

__global__ void scan_bsum_k(int* __restrict__ bsum, int nb) {
  __shared__ int s[512];
  int t = threadIdx.x;
  int v = (t < nb) ? bsum[t] : 0;
  s[t] = v; __syncthreads();
  for (int off = 1; off < 512; off <<= 1) {
    int a = (t >= off) ? s[t - off] : 0;
    __syncthreads();
    s[t] += a;
    __syncthreads();
  }
  if (t < nb) bsum[t] = s[t] - v;
}

__global__ void scan_add_k(int* __restrict__ rs, int* __restrict__ cursor,
                           const int* __restrict__ bsum) {
  int i = blockIdx.x * 256 + threadIdx.x;
  if (i < N_NODES) {
    int r = rs[i] + bsum[i >> 8];
    rs[i] = r;
    cursor[i] = r;
  }
}

__global__ void build_k(const int* __restrict__ src, const int* __restrict__ dst,
                        int* __restrict__ cursor, int* __restrict__ srcs) {
  int e = blockIdx.x * 256 + threadIdx.x;
  if (e < N_EDGES) {
    int d = dst[e];
    int p = atomicAdd(&cursor[d], 1);
    srcs[p] = src[e];
  }
}

__global__ void graph_starts_k(const int* __restrict__ batch, int* __restrict__ gstart) {
  int g = threadIdx.x;
  if (g > NGRAPH) return;
  if (g == NGRAPH) { gstart[NGRAPH] = N_NODES; return; }
  int lo = 0, hi = N_NODES;
  while (lo < hi) {
    int mid = (lo + hi) >> 1;
    if (batch[mid] < g) lo = mid + 1; else hi = mid;
  }
  gstart[g] = lo;
}

// ---------- MFMA bf16 GEMM: pre-transposed bf16 B, small LDS, high occupancy ----------
// Block = 64 rows x BN cols (BN = 16*NT), 4 waves, wave w owns rows [w*16, w*16+16).
// Bt is bf16 [F][K] (pre-transposed weights). Per K-tile (KT<=128 keeps LDS small ->
// 4-6 blocks/CU): issue A fragment loads (global->reg), copy B tile into LDS with
// straight coalesced uint4 copies, barrier, pure-MFMA compute (no barriers).
template <typename AT, int K, int KT, int NT, bool OUT_F32, int OCC>
__global__ __launch_bounds__(256, OCC)
void gemm_t(const AT* __restrict__ A, const unsigned short* __restrict__ Bt,
            const float* __restrict__ bias,
            const unsigned short* __restrict__ add1,
            const unsigned short* __restrict__ add2,
            void* __restrict__ Cv, int M, int F, int relu,
            const float* __restrict__ pe3src, unsigned short* __restrict__ C2) {
  constexpr int BN = 16 * NT;
  constexpr int KTILES = K / KT;
  constexpr int NSTEP = KT / 32;     // 32-k steps per tile
  constexpr int KC = KT / 8;         // 16B chunks per row
  constexpr int STK = KT + 8;        // (STK/2) mod 8 == 4 -> free 2-way LDS alias
  __shared__ unsigned short Bs[BN * STK];
  const int tid = threadIdx.x;
  const int wave = tid >> 6, lane = tid & 63;
  const int quad = lane >> 4, l16 = lane & 15;
  const int row0 = blockIdx.x * 64;
  const int col0 = blockIdx.y * BN;
  const int arow = row0 + wave * 16 + l16;
  const bool aok = arow < M;

  f32x4 acc[NT];
#pragma unroll
  for (int j = 0; j < NT; j++) acc[j] = (f32x4){0.f, 0.f, 0.f, 0.f};

#pragma unroll
  for (int kt = 0; kt < KTILES; ++kt) {
    if (kt) __syncthreads();  // protect LDS before overwrite

    // ---- A fragments for this K-tile: direct global->reg, issued first ----
    float4 av[sizeof(AT) == 4 ? 2 * NSTEP : 1];
    uint4 ah[sizeof(AT) == 4 ? 1 : NSTEP];
    if constexpr (sizeof(AT) == 4) {
      const float* ap = (const float*)A + (size_t)arow * K + kt * KT + quad * 8;
#pragma unroll
      for (int s = 0; s < NSTEP; s++) {
        av[2 * s] = aok ? *(const float4*)(ap + s * 32) : make_float4(0.f, 0.f, 0.f, 0.f);
        av[2 * s + 1] = aok ? *(const float4*)(ap + s * 32 + 4) : make_float4(0.f, 0.f, 0.f, 0.f);
      }
    } else {
      const unsigned short* ap = (const unsigned short*)A + (size_t)arow * K + kt * KT + quad * 8;
#pragma unroll
      for (int s = 0; s < NSTEP; s++)
        ah[s] = aok ? *(const uint4*)(ap + s * 32) : make_uint4(0, 0, 0, 0);
    }

    // ---- stage B tile: straight uint4 copy (coalesced, no conversion) ----
#pragma unroll
    for (int idx = tid; idx < BN * KC; idx += 256) {
      int n = idx / KC;
      int c = idx - n * KC;
      uint4 w = *(const uint4*)(Bt + (size_t)(col0 + n) * K + kt * KT + c * 8);
      *(uint4*)&Bs[n * STK + c * 8] = w;
    }
    __syncthreads();

    // ---- compute: zero barriers ----
#pragma unroll
    for (int s = 0; s < NSTEP; ++s) {
      bf16x8 afr;
      if constexpr (sizeof(AT) == 4) {
        uint4 t;
        t.x = pk2(av[2 * s].x, av[2 * s].y);
        t.y = pk2(av[2 * s].z, av[2 * s].w);
        t.z = pk2(av[2 * s + 1].x, av[2 * s + 1].y);
        t.w = pk2(av[2 * s + 1].z, av[2 * s + 1].w);
        afr = *(bf16x8*)&t;
      } else {
        afr = *(bf16x8*)&ah[s];
      }
#pragma unroll
      for (int nt = 0; nt < NT; nt++) {
        bf16x8 bfr = *(const bf16x8*)&Bs[(nt * 16 + l16) * STK + s * 32 + quad * 8];
        acc[nt] = __builtin_amdgcn_mfma_f32_16x16x32_bf16(afr, bfr, acc[nt], 0, 0, 0);
      }
    }
  }

  // ---- epilogue ----
  float* Cf = (float*)Cv;
  unsigned short* Ch = (unsigned short*)Cv;
#pragma unroll
  for (int r = 0; r < 4; r++) {
    int row = row0 + wave * 16 + quad * 4 + r;
    if (row >= M) continue;
#pragma unroll
    for (int nt = 0; nt < NT; nt++) {
      int col = col0 + nt * 16 + l16;
      float v = acc[nt][r];
      if (bias) v += bias[col];
      if (relu) v = fmaxf(v, 0.f);
      size_t off = (size_t)row * F + col;
      if (add1) v += bf2f(add1[off]);
      if (add2) v += bf2f(add2[off]);
      if (OUT_F32) Cf[off] = v; else Ch[off] = f2bf(v);
      if (C2) C2[off] = f2bf(v + pe3src[(size_t)row * 64 + (col & 63)]);
    }
  }
}

// ---------- small f32 GEMM (64x192x192 zg GEMM only) ----------
__global__ __launch_bounds__(256)
void gemm_kernel(const float* __restrict__ A, const float* __restrict__ B,
                 const float* __restrict__ bias, float* __restrict__ C,
                 int M, int K, int F) {
  __shared__ float Asm[16][65];
  __shared__ float Bsm[16][65];
  const int tid = threadIdx.x;
  const int tx = tid & 15, ty = tid >> 4;
  const int row0 = blockIdx.x * 64;
  const int col0 = blockIdx.y * 64;
  float acc[4][4];
#pragma unroll
  for (int i = 0; i < 4; i++)
#pragma unroll
    for (int j = 0; j < 4; j++) acc[i][j] = 0.f;

  for (int k0 = 0; k0 < K; k0 += 16) {
#pragma unroll
    for (int l = 0; l < 4; l++) {
      int idx = tid + l * 256;
      int m = idx >> 4, k = idx & 15;
      int r = row0 + m;
      Asm[k][m] = (r < M) ? A[(size_t)r * K + k0 + k] : 0.f;
    }
#pragma unroll
    for (int l = 0; l < 4; l++) {
      int idx = tid + l * 256;
      int k = idx >> 6, n = idx & 63;
      Bsm[k][n] = B[(size_t)(k0 + k) * F + col0 + n];
    }
    __syncthreads();
#pragma unroll
    for (int k = 0; k < 16; k++) {
      float a[4], b[4];
#pragma unroll
      for (int i = 0; i < 4; i++) a[i] = Asm[k][ty * 4 + i];
#pragma unroll
      for (int j = 0; j < 4; j++) b[j] = Bsm[k][tx * 4 + j];
#pragma unroll
      for (int i = 0; i < 4; i++)
#pragma unroll
        for (int j = 0; j < 4; j++) acc[i][j] += a[i] * b[j];
    }
    __syncthreads();
  }
#pragma unroll
  for (int i = 0; i < 4; i++) {
    int r = row0 + ty * 4 + i;
    if (r >= M) continue;
#pragma unroll
    for (int j = 0; j < 4; j++) {
      int c = col0 + tx * 4 + j;
      float v = acc[i][j];
      if (bias) v += bias[c];
      C[(size_t)r * F + c] = v;
    }
  }
}

// ---------- aggregations (bf16 in, f32 accumulate, bf16 out) ----------
template <int F>
__global__ void agg_mpnn_bf(const unsigned short* __restrict__ x, const int* __restrict__ rowstart,
                            const int* __restrict__ cnt, const int* __restrict__ srcs,
                            unsigned short* __restrict__ out) {
  constexpr int F8 = F / 8;
  int t = blockIdx.x * 256 + threadIdx.x;
  if (t >= N_NODES * F8) return;
  int i = t / F8, c = (t - i * F8) * 8;
  float a[8] = {0.f, 0.f, 0.f, 0.f, 0.f, 0.f, 0.f, 0.f};
  int e = rowstart[i], e1 = e + cnt[i];
  for (; e < e1; ++e) {
    int s = srcs[e];
    uint4 w = *(const uint4*)(x + (size_t)s * F + c);
    float f[8]; unpack8(w, f);
#pragma unroll
    for (int j = 0; j < 8; j++) a[j] += f[j];
  }
  *(uint4*)(out + (size_t)i * F + c) = pack8(a);
}

template <int F, bool RELU, bool HAS_BIAS>
__global__ void agg_gcn_bf(const unsigned short* __restrict__ x, const int* __restrict__ rowstart,
                           const int* __restrict__ cnt, const int* __restrict__ srcs,
                           const float* __restrict__ dinv, const float* __restrict__ bias,
                           unsigned short* __restrict__ out) {
  constexpr int F8 = F / 8;
  int t = blockIdx.x * 256 + threadIdx.x;
  if (t >= N_NODES * F8) return;
  int i = t / F8, c = (t - i * F8) * 8;
  float a[8] = {0.f, 0.f, 0.f, 0.f, 0.f, 0.f, 0.f, 0.f};
  int e = rowstart[i], e1 = e + cnt[i];
  for (; e < e1; ++e) {
    int s = srcs[e];
    float w = dinv[s];
    uint4 wv = *(const uint4*)(x + (size_t)s * F + c);
    float f[8]; unpack8(wv, f);
#pragma unroll
    for (int j = 0; j < 8; j++) a[j] += w * f[j];
  }
  float di = dinv[i];
  float sw = di * di;
  uint4 sv = *(const uint4*)(x + (size_t)i * F + c);
  float sf[8]; unpack8(sv, sf);
  float r[8];
#pragma unroll
  for (int j = 0; j < 8; j++) {
    float v = di * a[j] + sw * sf[j];
    if (HAS_BIAS) v += bias[c + j];
    if (RELU) v = fmaxf(v, 0.f);
    r[j] = v;
  }
  *(uint4*)(out + (size_t)i * F + c) = pack8(r);
}

// x2 aggregation: f32 input (32 cols), bf16 out
__global__ void agg_x2_k(const float* __restrict__ x, const int* __restrict__ rowstart,
                         const int* __restrict__ cnt, const int* __restrict__ srcs,
                         unsigned short* __restrict__ out) {
  int t = blockIdx.x * 256 + threadIdx.x;
  if (t >= N_NODES * 8) return;
  int i = t >> 3, c = (t & 7) * 4;
  float4 acc = make_float4(0.f, 0.f, 0.f, 0.f);
  int e = rowstart[i], e1 = e + cnt[i];
  for (; e < e1; ++e) {
    int s = srcs[e];
    float4 v = *(const float4*)(x + (size_t)s * 32 + c);
    acc.x += v.x; acc.y += v.y; acc.z += v.z; acc.w += v.w;
  }
  ushort4 o;
  o.x = f2bf(acc.x); o.y = f2bf(acc.y); o.z = f2bf(acc.z); o.w = f2bf(acc.w);
  *(ushort4*)(out + (size_t)i * 32 + c) = o;
}

// decoder GCN: source rows from 64-row f32 table zgW via batch.
// Fused dual output: out = z1_res (relu'd), out2 = z1_res + pe3.
__global__ void agg_gcn_dec_bf(const float* __restrict__ zgW, const int* __restrict__ rowstart,
                               const int* __restrict__ cnt, const int* __restrict__ srcs,
                               const int* __restrict__ batch, const float* __restrict__ dinv,
                               const float* __restrict__ bias, unsigned short* __restrict__ out,
                               const float* __restrict__ pe, unsigned short* __restrict__ out2) {
  int t = blockIdx.x * 256 + threadIdx.x;
  if (t >= N_NODES * 24) return;
  int i = t / 24, c = (t - i * 24) * 8;
  float a[8] = {0.f, 0.f, 0.f, 0.f, 0.f, 0.f, 0.f, 0.f};
  int e = rowstart[i], e1 = e + cnt[i];
  for (; e < e1; ++e) {
    int s = srcs[e];
    float w = dinv[s];
    const float* v = zgW + (size_t)batch[s] * 192 + c;
#pragma unroll
    for (int j = 0; j < 8; j++) a[j] += w * v[j];
  }
  float di = dinv[i];
  float sw = di * di;
  const float* sv = zgW + (size_t)batch[i] * 192 + c;
  float r[8];
#pragma unroll
  for (int j = 0; j < 8; j++)
    r[j] = fmaxf(di * a[j] + sw * sv[j] + bias[c + j], 0.f);
  *(uint4*)(out + (size_t)i * 192 + c) = pack8(r);
  // fused pe3 add: pe3[i, col] = pe[i, col & 63]; c is 8-aligned and 8|64 so
  // the 8-wide chunk never straddles a 64-boundary.
  const float* p = pe + (size_t)i * 64 + (c & 63);
  float r2[8];
#pragma unroll
  for (int j = 0; j < 8; j++) r2[j] = r[j] + p[j];
  *(uint4*)(out2 + (size_t)i * 192 + c) = pack8(r2);
}

// ---------- segment softmax (gate f32, z bf16) ----------
__global__ void init_gmax_k(unsigned* __restrict__ gmaxu) {
  int t = blockIdx.x * 256 + threadIdx.x;
  if (t < NGRAPH * 192) gmaxu[t] = 0x007FFFFFu;
}

__global__ void seg_max_k(const float* __restrict__ gate, const int* __restrict__ gstart,
                          unsigned* __restrict__ gmaxu) {
  int g = blockIdx.x, f = threadIdx.x;
  int lo = gstart[g], hi = gstart[g + 1];
  int len = hi - lo;
  if (len <= 0) return;
  int per = (len + gridDim.y - 1) / gridDim.y;
  int a = lo + blockIdx.y * per;
  int b = min(a + per, hi);
  if (a >= b) return;
  float m = -INFINITY;
  for (int i = a; i < b; i++) m = fmaxf(m, gate[(size_t)i * 192 + f]);
  atomicMax(&gmaxu[g * 192 + f], flip_f(m));
}

__global__ void seg_sum_k(const float* __restrict__ gate, const unsigned short* __restrict__ z,
                          const int* __restrict__ gstart, const unsigned* __restrict__ gmaxu,
                          float* __restrict__ esum, float* __restrict__ znum) {
  int g = blockIdx.x, f = threadIdx.x;
  int lo = gstart[g], hi = gstart[g + 1];
  int len = hi - lo;
  if (len <= 0) return;
  int per = (len + gridDim.y - 1) / gridDim.y;
  int a = lo + blockIdx.y * per;
  int b = min(a + per, hi);
  if (a >= b) return;
  float gm = unflip_f(gmaxu[g * 192 + f]);
  float se = 0.f, sz = 0.f;
  for (int i = a; i < b; i++) {
    float e = expf(gate[(size_t)i * 192 + f] - gm);
    se += e;
    sz += e * bf2f(z[(size_t)i * 192 + f]);
  }
  atomicAdd(&esum[g * 192 + f], se);
  atomicAdd(&znum[g * 192 + f], sz);
}

__global__ void zg_fin_k(const float* __restrict__ znum, const float* __restrict__ esum,
                         float* __restrict__ zg) {
  int t = blockIdx.x * 256 + threadIdx.x;
  if (t >= NGRAPH * 192) return;
  float es = esum[t];
  zg[t] = (es > 0.f) ? znum[t] / es : 0.f;
}

// ---------- launch ----------
extern "C" void kernel_launch(void* const* d_in, const int* in_sizes, int n_in,
                              void* d_out, int out_size, void* d_ws, size_t ws_size,
                              hipStream_t stream) {
  const float* x1 = (const float*)d_in[0];
  const float* x2 = (const float*)d_in[1];
  const float* pe = (const float*)d_in[2];
  const int* ei = (const int*)d_in[3];
  const int* src = ei;
  const int* dst = ei + N_EDGES;
  const int* batch = (const int*)d_in[4];
  const float* Wc  = (const float*)d_in[5];  const float* bc  = (const float*)d_in[6];
  const float* Wmf = (const float*)d_in[7];  const float* bmf = (const float*)d_in[8];
  const float* Wgf = (const float*)d_in[9];  const float* bgf = (const float*)d_in[10];
  const float* Wmc = (const float*)d_in[11]; const float* bmc = (const float*)d_in[12];
  const float* Wgc = (const float*)d_in[13]; const float* bgc = (const float*)d_in[14];
  const float* Wa1 = (const float*)d_in[15]; const float* ba1 = (const float*)d_in[16];
  const float* Wa2 = (const float*)d_in[17]; const float* ba2 = (const float*)d_in[18];
  const float* Wgd = (const float*)d_in[19]; const float* bgd = (const float*)d_in[20];
  const float* Wd1 = (const float*)d_in[21]; const float* bd1 = (const float*)d_in[22];
  const float* Wd2 = (const float*)d_in[23]; const float* bd2 = (const float*)d_in[24];
  const float* Wd3 = (const float*)d_in[25]; const float* bd3 = (const float*)d_in[26];
  float* out = (float*)d_out;

  char* base = (char*)d_ws;
  size_t woff = 0;
  auto walloc = [&](size_t bytes) -> void* {
    void* p = base + woff;
    woff = (woff + bytes + 255) & ~(size_t)255;
    return p;
  };
  unsigned short* P0h = (unsigned short*)walloc((size_t)N_NODES * 192 * 2); // x1_res -> z
  unsigned short* P1h = (unsigned short*)walloc((size_t)N_NODES * 256 * 2); // h/h1/a1/t1
  unsigned short* P2h = (unsigned short*)walloc((size_t)N_NODES * 192 * 2); // agg/t0/agg_b/agg_c
  unsigned short* P5a = (unsigned short*)walloc((size_t)N_NODES * 32 * 2);
  unsigned short* P5b = (unsigned short*)walloc((size_t)N_NODES * 64 * 2);
  unsigned short* P5c = (unsigned short*)walloc((size_t)N_NODES * 64 * 2);
  float* Pg   = (float*)walloc((size_t)N_NODES * 192 * 4);                  // gate (f32)
  float* dinv = (float*)walloc((size_t)N_NODES * 4);
  unsigned short* Wt = (unsigned short*)walloc((size_t)432128 * 2);         // bf16 [F][K] weights
  unsigned* gmaxu = (unsigned*)walloc((size_t)NGRAPH * 192 * 4);
  float* esum = (float*)walloc((size_t)NGRAPH * 192 * 4);
  float* znum = (float*)walloc((size_t)NGRAPH * 192 * 4);
  float* zg   = (float*)walloc((size_t)NGRAPH * 192 * 4);
  float* zgW  = (float*)walloc((size_t)NGRAPH * 192 * 4);
  int* cnt      = (int*)walloc((size_t)N_NODES * 4);
  int* rowstart = (int*)walloc((size_t)N_NODES * 4);
  int* cursor   = (int*)walloc((size_t)N_NODES * 4);
  int* srcs     = (int*)walloc((size_t)N_EDGES * 4);
  int* bsum     = (int*)walloc(512 * 4);
  int* gstart   = (int*)walloc(80 * 4);

  unsigned short* P3h = (unsigned short*)d_out;                            // lower half scratch
  unsigned short* P4h = (unsigned short*)((float*)d_out + (size_t)N_NODES * 192); // upper half

  // pre-transposed bf16 weight offsets (elements)
  const unsigned short* WtWc  = Wt + 0;
  const unsigned short* WtWmf = Wt + 73728;
  const unsigned short* WtWgf = Wt + 122880;
  const unsigned short* WtWmc = Wt + 172032;
  const unsigned short* WtWgc = Wt + 174080;
  const unsigned short* WtWa1 = Wt + 186368;
  const unsigned short* WtWa2 = Wt + 235520;
  const unsigned short* WtWd1 = Wt + 284672;
  const unsigned short* WtWd2 = Wt + 321536;
  const unsigned short* WtWd3 = Wt + 358400;

  const int TB = 256;
  hipMemsetAsync(cnt, 0, N_NODES * sizeof(int), stream);
  hipMemsetAsync(esum, 0, 2 * NGRAPH * 192 * sizeof(float), stream);

  WJobs jb;
  jb.src[0] = Wc;  jb.K[0] = 384; jb.F[0] = 192; jb.eoff[0] = 0;      jb.bend[0] = 288;
  jb.src[1] = Wmf; jb.K[1] = 192; jb.F[1] = 256; jb.eoff[1] = 73728;  jb.bend[1] = 480;
  jb.src[2] = Wgf; jb.K[2] = 256; jb.F[2] = 192; jb.eoff[2] = 122880; jb.bend[2] = 672;
  jb.src[3] = Wmc; jb.K[3] = 32;  jb.F[3] = 64;  jb.eoff[3] = 172032; jb.bend[3] = 680;
  jb.src[4] = Wgc; jb.K[4] = 64;  jb.F[4] = 192; jb.eoff[4] = 174080; jb.bend[4] = 728;
  jb.src[5] = Wa1; jb.K[5] = 192; jb.F[5] = 256; jb.eoff[5] = 186368; jb.bend[5] = 920;
  jb.src[6] = Wa2; jb.K[6] = 256; jb.F[6] = 192; jb.eoff[6] = 235520; jb.bend[6] = 1112;
  jb.src[7] = Wd1; jb.K[7] = 192; jb.F[7] = 192; jb.eoff[7] = 284672; jb.bend[7] = 1256;
  jb.src[8] = Wd2; jb.K[8] = 192; jb.F[8] = 192; jb.eoff[8] = 321536; jb.bend[8] = 1400;
  jb.src[9] = Wd3; jb.K[9] = 192; jb.F[9] = 384; jb.eoff[9] = 358400; jb.bend[9] = 1688;
  wconv_k<<<1688, 256, 0, stream>>>(jb, Wt);

  hist_k<<<(N_EDGES + TB - 1) / TB, TB, 0, stream>>>(dst, cnt);
  dinv_k<<<(N_NODES + TB - 1) / TB, TB, 0, stream>>>(cnt, dinv);
  int nb = (N_NODES + 255) / 256;
  scan_block_k<<<nb, 256, 0, stream>>>(cnt, rowstart, bsum);
  scan_bsum_k<<<1, 512, 0, stream>>>(bsum, nb);
  scan_add_k<<<nb, 256, 0, stream>>>(rowstart, cursor, bsum);
  build_k<<<(N_EDGES + TB - 1) / TB, TB, 0, stream>>>(src, dst, cursor, srcs);
  graph_starts_k<<<1, 128, 0, stream>>>(batch, gstart);

  const int mb64 = (N_NODES + 63) / 64;
  const int ew24 = (N_NODES * 24 + TB - 1) / TB;
  const int ew8 = (N_NODES * 8 + TB - 1) / TB;

  // ---- encoder ----
  // fused: P0h = relu(x1@Wc+bc), P1h = P0h + pe3   (K=384, KT=96, BN=192)
  gemm_t<float, 384, 96, 12, false, 4><<<mb64, 256, 0, stream>>>(x1, WtWc, bc, nullptr, nullptr, P0h, N_NODES, 192, 1, pe, P1h);
  agg_mpnn_bf<192><<<ew24, TB, 0, stream>>>(P1h, rowstart, cnt, srcs, P2h);
  gemm_t<unsigned short, 192, 96, 8, false, 6><<<dim3(mb64, 2), 256, 0, stream>>>(P2h, WtWmf, bmf, nullptr, nullptr, P1h, N_NODES, 256, 1, nullptr, nullptr);
  gemm_t<unsigned short, 256, 128, 6, false, 6><<<dim3(mb64, 2), 256, 0, stream>>>(P1h, WtWgf, nullptr, nullptr, nullptr, P3h, N_NODES, 192, 0, nullptr, nullptr);
  agg_gcn_bf<192, true, true><<<ew24, TB, 0, stream>>>(P3h, rowstart, cnt, srcs, dinv, bgf, P4h);
  agg_x2_k<<<ew8, TB, 0, stream>>>(x2, rowstart, cnt, srcs, P5a);
  gemm_t<unsigned short, 32, 32, 4, false, 6><<<mb64, 256, 0, stream>>>(P5a, WtWmc, bmc, nullptr, nullptr, P5b, N_NODES, 64, 1, nullptr, nullptr);
  agg_gcn_bf<64, false, false><<<ew8, TB, 0, stream>>>(P5b, rowstart, cnt, srcs, dinv, nullptr, P5c);
  // z = relu(cagg@Wgc + bgc) + h2 + x1_res  (in place over P0h)
  gemm_t<unsigned short, 64, 64, 6, false, 6><<<dim3(mb64, 2), 256, 0, stream>>>(P5c, WtWgc, bgc, P4h, P0h, P0h, N_NODES, 192, 1, nullptr, nullptr);

  // ---- attention aggregation ----
  gemm_t<unsigned short, 192, 96, 8, false, 6><<<dim3(mb64, 2), 256, 0, stream>>>(P0h, WtWa1, ba1, nullptr, nullptr, P1h, N_NODES, 256, 1, nullptr, nullptr);
  gemm_t<unsigned short, 256, 128, 6, true, 6><<<dim3(mb64, 2), 256, 0, stream>>>(P1h, WtWa2, ba2, nullptr, nullptr, Pg, N_NODES, 192, 0, nullptr, nullptr);
  init_gmax_k<<<(NGRAPH * 192 + TB - 1) / TB, TB, 0, stream>>>(gmaxu);
  dim3 sg(NGRAPH, 16);
  seg_max_k<<<sg, 192, 0, stream>>>(Pg, gstart, gmaxu);
  seg_sum_k<<<sg, 192, 0, stream>>>(Pg, P0h, gstart, gmaxu, esum, znum);
  zg_fin_k<<<(NGRAPH * 192 + TB - 1) / TB, TB, 0, stream>>>(znum, esum, zg);
  gemm_kernel<<<dim3(1, 3), 256, 0, stream>>>(zg, Wgd, nullptr, zgW, NGRAPH, 192, 192);

  // ---- decoder ----
  // fused: P4h = z1_res, P2h = z1_res + pe3
  agg_gcn_dec_bf<<<ew24, TB, 0, stream>>>(zgW, rowstart, cnt, srcs, batch, dinv, bgd, P4h, pe, P2h);
  agg_mpnn_bf<192><<<ew24, TB, 0, stream>>>(P2h, rowstart, cnt, srcs, P3h);
  gemm_t<unsigned short, 192, 96, 6, false, 6><<<dim3(mb64, 2), 256, 0, stream>>>(P3h, WtWd1, bd1, nullptr, nullptr, P1h, N_NODES, 192, 1, nullptr, nullptr);
  agg_mpnn_bf<192><<<ew24, TB, 0, stream>>>(P1h, rowstart, cnt, srcs, P2h);
  gemm_t<unsigned short, 192, 96, 6, false, 6><<<dim3(mb64, 2), 256, 0, stream>>>(P2h, WtWd2, bd2, P4h, nullptr, P3h, N_NODES, 192, 1, nullptr, nullptr);
  agg_mpnn_bf<192><<<ew24, TB, 0, stream>>>(P3h, rowstart, cnt, srcs, P2h);
  gemm_t<unsigned short, 192, 96, 8, true, 6><<<dim3(mb64, 3), 256, 0, stream>>>(P2h, WtWd3, bd3, nullptr, nullptr, out, N_NODES, 384, 1, nullptr, nullptr);
  (void)in_sizes; (void)n_in; (void)out_size; (void)ws_size;
}